// Round 3
// baseline (228.907 us; speedup 1.0000x reference)
//
#include <hip/hip_runtime.h>
#include <hip/hip_bf16.h>

// Problem constants (match reference setup_inputs)
#define Bn 8
#define Nn 131072
#define Cn 20
#define Kn 20

#define THREADS 256
#define GRID 2048                              // 8 blocks/CU -> 32 waves/CU (HW max)
#define BLOCKS_PER_BATCH (GRID / Bn)           // 256
#define CHUNK (Nn / BLOCKS_PER_BATCH)          // 512 points per block
#define EPB (CHUNK / THREADS)                  // 2 per thread

// LDS bin replication: 8 copies indexed by lane&7, field-major with pad.
// acc[r][f*21 + k]; stride 84 floats -> replica bank offsets 20r mod 32
// = {0,20,8,28,16,4,24,12}, all distinct.
#define NREP 8
#define RSTRIDE 84

// ws layout (floats):
#define WS_SEG 0                     // [B*K*4): x,y,z,count per (b,k)
#define WS_SEM (Bn * Kn * 4)         // 640
#define WS_CSV (WS_SEM + 1)          // 641
#define WS_TICKET (WS_SEM + 2)       // 642 (int)
#define WS_FLOATS (WS_SEM + 3)

// Pass 1: sem-loss gather-sum + per-(b,k) point sums & counts.
__global__ void __launch_bounds__(THREADS) loss_pass1(
    const float* __restrict__ points,
    const float* __restrict__ sem,
    const int* __restrict__ label,
    float* __restrict__ ws) {
    __shared__ float acc[NREP][RSTRIDE];
    __shared__ float wsum[4];

    const int tid  = threadIdx.x;
    const int wave = tid >> 6;
    const int lane = tid & 63;
    const int rep  = lane & (NREP - 1);

    for (int i = tid; i < NREP * RSTRIDE; i += THREADS) ((float*)acc)[i] = 0.0f;
    __syncthreads();

    const int b  = blockIdx.x / BLOCKS_PER_BATCH;
    const int n0 = (blockIdx.x % BLOCKS_PER_BATCH) * CHUNK;
    const int* lab = label + (long)b * 2 * Nn;

    float semsum = 0.0f;
#pragma unroll
    for (int e = 0; e < EPB; ++e) {
        const int n    = n0 + e * THREADS + tid;
        const int cls  = lab[n];
        const int inst = lab[Nn + n];
        const long rowb = (long)b * Nn + n;
        semsum += __builtin_nontemporal_load(&sem[rowb * Cn + cls]);
        const float3 p = ((const float3*)points)[rowb];
        float* a = acc[rep];
        atomicAdd(&a[0 * 21 + inst], p.x);
        atomicAdd(&a[1 * 21 + inst], p.y);
        atomicAdd(&a[2 * 21 + inst], p.z);
        atomicAdd(&a[3 * 21 + inst], 1.0f);
    }
    __syncthreads();

    // flush: sum 8 replicas -> one global atomic per (k,f); 80 lanes active
    if (tid < Kn * 4) {
        const int k = tid >> 2, f = tid & 3;
        float v = 0.0f;
#pragma unroll
        for (int r = 0; r < NREP; ++r) v += acc[r][f * 21 + k];
        atomicAdd(&ws[WS_SEG + (b * Kn + k) * 4 + f], v);
    }

    // block-reduce semsum, one global atomic per block
#pragma unroll
    for (int off = 32; off > 0; off >>= 1) semsum += __shfl_down(semsum, off);
    if (lane == 0) wsum[wave] = semsum;
    __syncthreads();
    if (tid == 0) atomicAdd(&ws[WS_SEM], wsum[0] + wsum[1] + wsum[2] + wsum[3]);
}

// Pass 2: centers = sum/max(cnt,1); csv loss sum; last block finalizes out.
__global__ void __launch_bounds__(THREADS) loss_pass2(
    const float* __restrict__ points,
    const float* __restrict__ pcsv,
    const int* __restrict__ label,
    float* __restrict__ ws,
    float* __restrict__ out) {
    __shared__ float ctr[Kn][3];
    __shared__ float wsum[4];

    const int tid  = threadIdx.x;
    const int wave = tid >> 6;
    const int lane = tid & 63;
    const int b    = blockIdx.x / BLOCKS_PER_BATCH;

    if (tid < Kn) {
        const float* s = ws + WS_SEG + (b * Kn + tid) * 4;
        const float inv = 1.0f / fmaxf(s[3], 1.0f);
        ctr[tid][0] = s[0] * inv;
        ctr[tid][1] = s[1] * inv;
        ctr[tid][2] = s[2] * inv;
    }
    __syncthreads();

    const int n0 = (blockIdx.x % BLOCKS_PER_BATCH) * CHUNK;
    const int* inst_lab = label + (long)b * 2 * Nn + Nn;

    float lsum = 0.0f;
#pragma unroll
    for (int e = 0; e < EPB; ++e) {
        const int n    = n0 + e * THREADS + tid;
        const int inst = inst_lab[n];
        const long rowb = (long)b * Nn + n;
        const float3 p = ((const float3*)points)[rowb];
        const float3 q = ((const float3*)pcsv)[rowb];
        const float dx = ctr[inst][0] - p.x;
        const float dy = ctr[inst][1] - p.y;
        const float dz = ctr[inst][2] - p.z;
        const float nd = sqrtf(dx * dx + dy * dy + dz * dz);
        const float w  = fminf(nd, 1.0f);
        const float ex = dx - q.x;
        const float ey = dy - q.y;
        const float ez = dz - q.z;
        lsum += sqrtf(ex * ex + ey * ey + ez * ez) * w;
    }

#pragma unroll
    for (int off = 32; off > 0; off >>= 1) lsum += __shfl_down(lsum, off);
    if (lane == 0) wsum[wave] = lsum;
    __syncthreads();

    if (tid == 0) {
        atomicAdd(&ws[WS_CSV], wsum[0] + wsum[1] + wsum[2] + wsum[3]);
        __threadfence();
        int* ticket = (int*)&ws[WS_TICKET];
        const int t = atomicAdd(ticket, 1);
        if (t == GRID - 1) {
            // last block: read accumulators at the coherent point, finalize
            const float s = atomicAdd(&ws[WS_SEM], 0.0f);
            const float c = atomicAdd(&ws[WS_CSV], 0.0f);
            const float invBN = 1.0f / (float)((long)Bn * Nn);
            out[0] = -s * invBN + 0.2f * c * invBN;
        }
    }
}

extern "C" void kernel_launch(void* const* d_in, const int* in_sizes, int n_in,
                              void* d_out, int out_size, void* d_ws, size_t ws_size,
                              hipStream_t stream) {
    const float* points = (const float*)d_in[0];
    const float* sem    = (const float*)d_in[1];
    const float* pcsv   = (const float*)d_in[2];
    const int*   label  = (const int*)d_in[3];
    float* ws  = (float*)d_ws;
    float* out = (float*)d_out;

    hipMemsetAsync(d_ws, 0, WS_FLOATS * sizeof(float), stream);
    loss_pass1<<<GRID, THREADS, 0, stream>>>(points, sem, label, ws);
    loss_pass2<<<GRID, THREADS, 0, stream>>>(points, pcsv, label, ws, out);
}

// Round 5
// 158.137 us; speedup vs baseline: 1.4475x; 1.4475x over previous
//
#include <hip/hip_runtime.h>
#include <hip/hip_bf16.h>

// Problem constants (match reference setup_inputs)
#define Bn 8
#define Nn 131072
#define Cn 20
#define Kn 20

#define THREADS 256
#define GRID 2048                              // 8 blocks/CU -> 32 waves/CU
#define BLOCKS_PER_BATCH (GRID / Bn)           // 256
#define CHUNK (Nn / BLOCKS_PER_BATCH)          // 512 points per block
#define EPB (CHUNK / THREADS)                  // 2 per thread

// LDS bin replication: 8 copies indexed by lane&7, field-major with pad.
// acc[r][f*21 + k]; stride 84 floats -> replica bank offsets 20r mod 32
// = {0,20,8,28,16,4,24,12}, all distinct.
#define NREP 8
#define RSTRIDE 84

// ws layout (floats). NO same-address scalar atomics anywhere:
// per-block partials go to unique slots, reduced by loss_final.
#define WS_SEG 0                     // [640): x,y,z,count per (b,k) (atomics, 640 addrs)
#define WS_SEMP 640                  // [2048) per-block sem partials (plain stores)
#define WS_CSVP (640 + GRID)         // [2048) per-block csv partials (plain stores)
#define WS_ZERO_FLOATS 640           // only the segment bins need zeroing

// Pass 1: sem-loss gather-sum + per-(b,k) point sums & counts.
__global__ void __launch_bounds__(THREADS) loss_pass1(
    const float* __restrict__ points,
    const float* __restrict__ sem,
    const int* __restrict__ label,
    float* __restrict__ ws) {
    __shared__ float acc[NREP][RSTRIDE];
    __shared__ float wsum[4];

    const int tid  = threadIdx.x;
    const int wave = tid >> 6;
    const int lane = tid & 63;
    const int rep  = lane & (NREP - 1);

    for (int i = tid; i < NREP * RSTRIDE; i += THREADS) ((float*)acc)[i] = 0.0f;
    __syncthreads();

    const int b  = blockIdx.x / BLOCKS_PER_BATCH;
    const int n0 = (blockIdx.x % BLOCKS_PER_BATCH) * CHUNK;
    const int* lab = label + (long)b * 2 * Nn;

    float semsum = 0.0f;
#pragma unroll
    for (int e = 0; e < EPB; ++e) {
        const int n    = n0 + e * THREADS + tid;
        const int cls  = lab[n];
        const int inst = lab[Nn + n];
        const long rowb = (long)b * Nn + n;
        semsum += __builtin_nontemporal_load(&sem[rowb * Cn + cls]);
        const float3 p = ((const float3*)points)[rowb];
        float* a = acc[rep];
        atomicAdd(&a[0 * 21 + inst], p.x);
        atomicAdd(&a[1 * 21 + inst], p.y);
        atomicAdd(&a[2 * 21 + inst], p.z);
        atomicAdd(&a[3 * 21 + inst], 1.0f);
    }
    __syncthreads();

    // flush: sum 8 replicas -> one global atomic per (k,f); 640 distinct
    // addresses across the grid, <=256 collisions each -> parallel at L2.
    if (tid < Kn * 4) {
        const int k = tid >> 2, f = tid & 3;
        float v = 0.0f;
#pragma unroll
        for (int r = 0; r < NREP; ++r) v += acc[r][f * 21 + k];
        atomicAdd(&ws[WS_SEG + (b * Kn + k) * 4 + f], v);
    }

    // block-reduce semsum -> UNIQUE slot, plain store (no contention)
#pragma unroll
    for (int off = 32; off > 0; off >>= 1) semsum += __shfl_down(semsum, off);
    if (lane == 0) wsum[wave] = semsum;
    __syncthreads();
    if (tid == 0) ws[WS_SEMP + blockIdx.x] = wsum[0] + wsum[1] + wsum[2] + wsum[3];
}

// Pass 2: centers = sum/max(cnt,1); csv partial -> unique slot.
__global__ void __launch_bounds__(THREADS) loss_pass2(
    const float* __restrict__ points,
    const float* __restrict__ pcsv,
    const int* __restrict__ label,
    float* __restrict__ ws) {
    __shared__ float ctr[Kn][3];
    __shared__ float wsum[4];

    const int tid  = threadIdx.x;
    const int wave = tid >> 6;
    const int lane = tid & 63;
    const int b    = blockIdx.x / BLOCKS_PER_BATCH;

    if (tid < Kn) {
        const float* s = ws + WS_SEG + (b * Kn + tid) * 4;
        const float inv = 1.0f / fmaxf(s[3], 1.0f);
        ctr[tid][0] = s[0] * inv;
        ctr[tid][1] = s[1] * inv;
        ctr[tid][2] = s[2] * inv;
    }
    __syncthreads();

    const int n0 = (blockIdx.x % BLOCKS_PER_BATCH) * CHUNK;
    const int* inst_lab = label + (long)b * 2 * Nn + Nn;

    float lsum = 0.0f;
#pragma unroll
    for (int e = 0; e < EPB; ++e) {
        const int n    = n0 + e * THREADS + tid;
        const int inst = inst_lab[n];
        const long rowb = (long)b * Nn + n;
        const float3 p = ((const float3*)points)[rowb];
        const float3 q = ((const float3*)pcsv)[rowb];
        const float dx = ctr[inst][0] - p.x;
        const float dy = ctr[inst][1] - p.y;
        const float dz = ctr[inst][2] - p.z;
        const float nd = sqrtf(dx * dx + dy * dy + dz * dz);
        const float w  = fminf(nd, 1.0f);
        const float ex = dx - q.x;
        const float ey = dy - q.y;
        const float ez = dz - q.z;
        lsum += sqrtf(ex * ex + ey * ey + ez * ez) * w;
    }

#pragma unroll
    for (int off = 32; off > 0; off >>= 1) lsum += __shfl_down(lsum, off);
    if (lane == 0) wsum[wave] = lsum;
    __syncthreads();
    if (tid == 0) ws[WS_CSVP + blockIdx.x] = wsum[0] + wsum[1] + wsum[2] + wsum[3];
}

// Finalize: reduce 2x2048 per-block partials, write the scalar loss.
__global__ void __launch_bounds__(THREADS) loss_final(
    const float* __restrict__ ws, float* __restrict__ out) {
    __shared__ float ssum[4], csum[4];
    const int tid  = threadIdx.x;
    const int wave = tid >> 6;
    const int lane = tid & 63;

    float s = 0.0f, c = 0.0f;
#pragma unroll
    for (int i = 0; i < GRID / THREADS; ++i) {
        s += ws[WS_SEMP + i * THREADS + tid];
        c += ws[WS_CSVP + i * THREADS + tid];
    }
#pragma unroll
    for (int off = 32; off > 0; off >>= 1) {
        s += __shfl_down(s, off);
        c += __shfl_down(c, off);
    }
    if (lane == 0) { ssum[wave] = s; csum[wave] = c; }
    __syncthreads();
    if (tid == 0) {
        const float S = ssum[0] + ssum[1] + ssum[2] + ssum[3];
        const float C = csum[0] + csum[1] + csum[2] + csum[3];
        const float invBN = 1.0f / (float)((long)Bn * Nn);
        out[0] = -S * invBN + 0.2f * C * invBN;
    }
}

extern "C" void kernel_launch(void* const* d_in, const int* in_sizes, int n_in,
                              void* d_out, int out_size, void* d_ws, size_t ws_size,
                              hipStream_t stream) {
    const float* points = (const float*)d_in[0];
    const float* sem    = (const float*)d_in[1];
    const float* pcsv   = (const float*)d_in[2];
    const int*   label  = (const int*)d_in[3];
    float* ws  = (float*)d_ws;
    float* out = (float*)d_out;

    hipMemsetAsync(d_ws, 0, WS_ZERO_FLOATS * sizeof(float), stream);
    loss_pass1<<<GRID, THREADS, 0, stream>>>(points, sem, label, ws);
    loss_pass2<<<GRID, THREADS, 0, stream>>>(points, pcsv, label, ws);
    loss_final<<<1, THREADS, 0, stream>>>(ws, out);
}